// Round 1
// 694.506 us; speedup vs baseline: 1.0046x; 1.0046x over previous
//
#include <hip/hip_runtime.h>

#define LL 200      // history length
#define DD 128      // attention dim
#define NH 4        // heads
#define RSCALE 0.17677669529663687f   // 1/sqrt(32)

__device__ __forceinline__ float blo(unsigned int u) { return __uint_as_float(u << 16); }
__device__ __forceinline__ float bhi(unsigned int u) { return __uint_as_float(u & 0xffff0000u); }
__device__ __forceinline__ float b2f(unsigned short u) { return __uint_as_float(((unsigned int)u) << 16); }
__device__ __forceinline__ unsigned short f2bf(float f) {
  unsigned int u = __float_as_uint(f);
  u += 0x7fffu + ((u >> 16) & 1u);   // RNE
  return (unsigned short)(u >> 16);
}

// dot of a 128-wide weight row (bf16 or f32) with a 128-float LDS vector
template <bool F32>
__device__ __forceinline__ float rowdot128(const void* __restrict__ wrow,
                                           const float* __restrict__ v) {
  float acc = 0.f;
  if constexpr (F32) {
    const float4* wr = (const float4*)wrow;
#pragma unroll
    for (int k = 0; k < 32; k++) {
      float4 w = wr[k];
      float4 vv = *(const float4*)(v + 4 * k);
      acc += w.x * vv.x + w.y * vv.y + w.z * vv.z + w.w * vv.w;
    }
  } else {
    const uint4* wr = (const uint4*)wrow;
#pragma unroll
    for (int k = 0; k < 16; k++) {
      uint4 u = wr[k];
      float4 v0 = *(const float4*)(v + k * 8);
      float4 v1 = *(const float4*)(v + k * 8 + 4);
      acc += blo(u.x) * v0.x + bhi(u.x) * v0.y + blo(u.y) * v0.z + bhi(u.y) * v0.w;
      acc += blo(u.z) * v1.x + bhi(u.z) * v1.y + blo(u.w) * v1.z + bhi(u.w) * v1.w;
    }
  }
  return acc;
}

template <bool F32>
__device__ __forceinline__ float welem(const void* w, size_t idx) {
  if constexpr (F32) return ((const float*)w)[idx];
  else               return b2f(((const unsigned short*)w)[idx]);
}

// Small shared footprint -> 5 blocks/CU (was 61KB -> 2 blocks/CU)
struct __align__(16) Smem {
  float qt[DD * NH];      // 2048B  q~ as [j][h]; reused as cvec[512] after phase D
  float sc[LL * NH];      // 3200B  scores -> attn, [l][h]
  float tvec[DD];         // 512B   target f32; reused as ovec
  float qv[DD];           // 512B   q = Wq*t
  float cpart[4 * 512];   // 8192B  c partials (4 l-chunks)
  int flag;               // dtype verdict (1 = f32)
};

template <bool F32>
__device__ __forceinline__ void body(Smem& sm, const int tid, const int b,
                                     const void* __restrict__ tgt,
                                     const void* __restrict__ hist,
                                     const int* __restrict__ mask,
                                     const void* __restrict__ Wq,
                                     const void* __restrict__ Wk,
                                     const void* __restrict__ Wv,
                                     const void* __restrict__ Wo,
                                     void* __restrict__ out) {
  const float NINF = -__builtin_inff();

  // P0: target row -> f32 LDS
  if (tid < DD) sm.tvec[tid] = welem<F32>(tgt, (size_t)b * DD + tid);
  __syncthreads();

  // P1: q[i] = Wq[i,:] . t
  if (tid < DD)
    sm.qv[tid] = rowdot128<F32>((const char*)Wq + (size_t)tid * DD * (F32 ? 4 : 2), sm.tvec);
  __syncthreads();

  // P2: q~[j][h] = (1/sqrt(32)) * sum_d q[h*32+d] * Wk[h*32+d][j]  (transposed layout)
  for (int e = tid; e < NH * DD; e += 256) {
    const int h = e >> 7, j = e & 127;
    float acc = 0.f;
#pragma unroll 8
    for (int d = 0; d < 32; d++)
      acc += sm.qv[h * 32 + d] * welem<F32>(Wk, (size_t)(h * 32 + d) * DD + j);
    sm.qt[j * NH + h] = acc * RSCALE;
  }
  __syncthreads();

  // Phase B: scores[l][h] = q~ . hist[l]  (thread = row; hist straight from global)
  if (tid < LL) {
    const int l = tid;
    float a0 = 0.f, a1 = 0.f, a2 = 0.f, a3 = 0.f;
#define QACC(JE, FV) { float4 q_ = *(const float4*)&sm.qt[(JE) * 4]; const float f_ = (FV); \
  a0 += f_ * q_.x; a1 += f_ * q_.y; a2 += f_ * q_.z; a3 += f_ * q_.w; }
    if constexpr (!F32) {
      const uint4* hr = (const uint4*)((const unsigned short*)hist + (size_t)(b * LL + l) * DD);
#pragma unroll
      for (int c = 0; c < 2; c++) {
        uint4 u[8];
#pragma unroll
        for (int k = 0; k < 8; k++) u[k] = hr[c * 8 + k];
#pragma unroll
        for (int k = 0; k < 8; k++) {
          const int jb = c * 64 + k * 8;
          QACC(jb + 0, blo(u[k].x)); QACC(jb + 1, bhi(u[k].x));
          QACC(jb + 2, blo(u[k].y)); QACC(jb + 3, bhi(u[k].y));
          QACC(jb + 4, blo(u[k].z)); QACC(jb + 5, bhi(u[k].z));
          QACC(jb + 6, blo(u[k].w)); QACC(jb + 7, bhi(u[k].w));
        }
      }
    } else {
      const float4* hr = (const float4*)((const float*)hist + (size_t)(b * LL + l) * DD);
#pragma unroll
      for (int c = 0; c < 4; c++) {
        float4 u[8];
#pragma unroll
        for (int k = 0; k < 8; k++) u[k] = hr[c * 8 + k];
#pragma unroll
        for (int k = 0; k < 8; k++) {
          const int jb = c * 32 + k * 4;
          QACC(jb + 0, u[k].x); QACC(jb + 1, u[k].y);
          QACC(jb + 2, u[k].z); QACC(jb + 3, u[k].w);
        }
      }
    }
#undef QACC
    const bool mv = mask[(size_t)b * LL + l] != 0;
    float4 sv;
    sv.x = mv ? a0 : NINF;
    sv.y = mv ? a1 : NINF;
    sv.z = mv ? a2 : NINF;
    sv.w = mv ? a3 : NINF;
    *(float4*)&sm.sc[l * 4] = sv;
  }
  __syncthreads();

  // P5: per-head masked softmax over l (wave h = head h; shuffle reductions)
  {
    const int h = tid >> 6, lane = tid & 63;
    float v0 = sm.sc[lane * 4 + h];
    float v1 = sm.sc[(lane + 64) * 4 + h];
    float v2 = sm.sc[(lane + 128) * 4 + h];
    float v3 = (lane < 8) ? sm.sc[(lane + 192) * 4 + h] : NINF;
    float m = fmaxf(fmaxf(v0, v1), fmaxf(v2, v3));
#pragma unroll
    for (int off = 32; off; off >>= 1) m = fmaxf(m, __shfl_xor(m, off));
    float e0 = __expf(v0 - m), e1 = __expf(v1 - m), e2 = __expf(v2 - m);
    float e3 = (lane < 8) ? __expf(v3 - m) : 0.f;
    float s = e0 + e1 + e2 + e3;
#pragma unroll
    for (int off = 32; off; off >>= 1) s += __shfl_xor(s, off);
    const float r = 1.f / s;
    sm.sc[lane * 4 + h] = e0 * r;
    sm.sc[(lane + 64) * 4 + h] = e1 * r;
    sm.sc[(lane + 128) * 4 + h] = e2 * r;
    if (lane < 8) sm.sc[(lane + 192) * 4 + h] = e3 * r;
  }
  __syncthreads();

  // Phase D: c[h][j] = sum_l attn[h][l] * hist[l][j]
  // thread = column pair j2, 4 l-chunks; 2nd global pass -> L2/L3-resident
  {
    const int j2 = tid & 63;
    const int ch = tid >> 6;
    const int l0 = ch * 50;
    float a00=0.f,a01=0.f,a10=0.f,a11=0.f,a20=0.f,a21=0.f,a30=0.f,a31=0.f;
    if constexpr (!F32) {
      const unsigned int* hd =
          (const unsigned int*)((const unsigned short*)hist + (size_t)b * LL * DD) + j2;
#pragma unroll 5
      for (int l = l0; l < l0 + 50; l++) {
        const unsigned int dw = hd[l * 64];
        const float f0 = blo(dw), f1 = bhi(dw);
        const float4 at = *(const float4*)&sm.sc[l * 4];   // wave-uniform broadcast
        a00 += f0 * at.x; a01 += f1 * at.x;
        a10 += f0 * at.y; a11 += f1 * at.y;
        a20 += f0 * at.z; a21 += f1 * at.z;
        a30 += f0 * at.w; a31 += f1 * at.w;
      }
    } else {
      const float2* hf = (const float2*)((const float*)hist + (size_t)b * LL * DD) + j2;
#pragma unroll 5
      for (int l = l0; l < l0 + 50; l++) {
        const float2 f = hf[l * 64];
        const float4 at = *(const float4*)&sm.sc[l * 4];
        a00 += f.x * at.x; a01 += f.y * at.x;
        a10 += f.x * at.y; a11 += f.y * at.y;
        a20 += f.x * at.z; a21 += f.y * at.z;
        a30 += f.x * at.w; a31 += f.y * at.w;
      }
    }
    float* cp = &sm.cpart[ch * 512];
    const int j = 2 * j2;
    *(float2*)&cp[0 * DD + j] = make_float2(a00, a01);
    *(float2*)&cp[1 * DD + j] = make_float2(a10, a11);
    *(float2*)&cp[2 * DD + j] = make_float2(a20, a21);
    *(float2*)&cp[3 * DD + j] = make_float2(a30, a31);
  }
  __syncthreads();

  // P7a: reduce chunk partials -> cvec (aliases qt, dead after Phase B)
  float* cvec = sm.qt;
  for (int idx = tid; idx < 512; idx += 256)
    cvec[idx] = sm.cpart[idx] + sm.cpart[512 + idx] + sm.cpart[1024 + idx] + sm.cpart[1536 + idx];
  __syncthreads();

  // P7b: o[i] = Wv[i,:] . c[head(i)]  (ovec aliases tvec)
  if (tid < DD)
    sm.tvec[tid] = rowdot128<F32>((const char*)Wv + (size_t)tid * DD * (F32 ? 4 : 2),
                                  &cvec[(tid >> 5) * DD]);
  __syncthreads();

  // P8: out[i'] = Wo[i',:] . o
  if (tid < DD) {
    const float acc = rowdot128<F32>((const char*)Wo + (size_t)tid * DD * (F32 ? 4 : 2), sm.tvec);
    if constexpr (F32) ((float*)out)[(size_t)b * DD + tid] = acc;
    else               ((unsigned short*)out)[(size_t)b * DD + tid] = f2bf(acc);
  }
}

// Single fused kernel: per-block inline dtype probe (no separate detect launch,
// no dead template dispatch). Probe: for bf16 data the low half of each dword is
// a bf16 normal (exp in [110,134] essentially always); f32 mantissa bits ~10%.
__global__ __launch_bounds__(256, 5)
void mhta_kernel(const void* __restrict__ tgt,   // [B,128]
                 const void* __restrict__ hist,  // [B,200,128]
                 const int* __restrict__ mask,   // [B,200] i32
                 const void* __restrict__ Wq,    // [128,128]
                 const void* __restrict__ Wk,
                 const void* __restrict__ Wv,
                 const void* __restrict__ Wo,
                 void* __restrict__ out)         // [B,128]
{
  __shared__ Smem sm;
  const int tid = threadIdx.x;
  const int b = blockIdx.x;

  if (tid < 64) {
    // sample 64 dwords of this block's own history (bf16-offset is in-bounds
    // for f32 data too, and contains valid f32 words there)
    const unsigned int* hd = (const unsigned int*)((const char*)hist + (size_t)b * LL * DD * 2);
    const unsigned int e = (hd[tid] >> 7) & 0xffu;
    const unsigned long long bal = __ballot(e >= 110u && e <= 134u);
    if (tid == 0) sm.flag = (__popcll(bal) < 32) ? 1 : 0;
  }
  __syncthreads();

  if (sm.flag) body<true >(sm, tid, b, tgt, hist, mask, Wq, Wk, Wv, Wo, out);
  else         body<false>(sm, tid, b, tgt, hist, mask, Wq, Wk, Wv, Wo, out);
}

extern "C" void kernel_launch(void* const* d_in, const int* in_sizes, int n_in,
                              void* d_out, int out_size, void* d_ws, size_t ws_size,
                              hipStream_t stream) {
  const void* tgt  = d_in[0];
  const void* hist = d_in[1];
  const int*  mask = (const int*)d_in[2];
  const void* Wq   = d_in[3];
  const void* Wk   = d_in[4];
  const void* Wv   = d_in[5];
  const void* Wo   = d_in[6];

  const int B = in_sizes[0] / DD;   // 4096

  mhta_kernel<<<dim3(B), dim3(256), 0, stream>>>(tgt, hist, mask, Wq, Wk, Wv, Wo, d_out);
}